// Round 2
// baseline (338.519 us; speedup 1.0000x reference)
//
#include <hip/hip_runtime.h>
#include <cstdint>
#include <cstddef>

// SSMLayer, round 2:
//   LN -> fused GEMM (xn @ [W_in | W_in@Wcat] -> xp bf16 + proj fp32 planar)
//      -> chunked parallel scan (L=32, 128 chunks) -> CH bf16
//      -> output GEMM  out = [CH|xp] @ [W_so@W_out | D.*W_out]^T + b_out + x
// GEMMs: bf16 MFMA 16x16x32, fp32 accumulate, 128x128 tile, BK=64,
// XOR-swizzled LDS, global_load_lds width-16. Scan fp32.

typedef unsigned short bf16_t;
typedef __attribute__((ext_vector_type(8))) short bh8;
typedef __attribute__((ext_vector_type(4))) float f4;

#define M_ROWS 32768
#define SCAN_L 32
#define SCAN_C 128   // 4096 / SCAN_L

__device__ __forceinline__ unsigned short f2bf(float f) {
  union { float f; unsigned int u; } c; c.f = f;
  unsigned int u = c.u;
  return (unsigned short)((u + 0x7FFFu + ((u >> 16) & 1u)) >> 16);
}

__device__ __forceinline__ void async_cp16(void* lds, const void* g) {
  __builtin_amdgcn_global_load_lds((const __attribute__((address_space(1))) void*)g,
                                   (__attribute__((address_space(3))) void*)lds, 16, 0, 0);
}

// ---------------- prep_a: transpose W_in, K-split partials for W1/Wfuse, Abar ----
// seg0 262144: Wbig[n][k] = W_in[k][n]            (rows 0..511)
// seg1 131072: W1p[s][k][n]  partial W_so@W_out   (s in 0..3, j = s*128..+128)
// seg2 393216: Wfp[s][d][n]  partial W_in@Wcat    (n in 0..191)
// seg3     64: Abar = exp(-exp(A_log)), Apow = Abar^SCAN_L
__global__ __launch_bounds__(256) void prep_a(
    const float* __restrict__ W_in, const float* __restrict__ W_xs,
    const float* __restrict__ W_B,  const float* __restrict__ W_C,
    const float* __restrict__ W_so, const float* __restrict__ W_out,
    const float* __restrict__ A_log,
    bf16_t* __restrict__ Wbig, float* __restrict__ W1p, float* __restrict__ Wfp,
    float* __restrict__ Abar, float* __restrict__ Apow) {
  int i = blockIdx.x * 256 + threadIdx.x;
  if (i < 512 * 512) {
    int n = i >> 9, k = i & 511;
    Wbig[n * 512 + k] = f2bf(W_in[k * 512 + n]);
    return;
  }
  i -= 512 * 512;
  if (i < 4 * 64 * 512) {
    int s = i >> 15, r = i & 32767, k = r >> 9, n = r & 511;
    float acc = 0.f;
    const int j0 = s * 128;
    for (int j = j0; j < j0 + 128; ++j)
      acc = fmaf(W_so[k * 512 + j], W_out[j * 512 + n], acc);
    W1p[i] = acc;
    return;
  }
  i -= 4 * 64 * 512;
  if (i < 4 * 512 * 192) {
    int s = i / (512 * 192), r = i - s * 512 * 192, d = r / 192, n = r - d * 192;
    float acc = 0.f;
    const int j0 = s * 128;
    for (int j = j0; j < j0 + 128; ++j) {
      float v = (n < 64) ? W_xs[j * 64 + n]
              : (n < 128) ? W_B[j * 64 + n - 64] : W_C[j * 64 + n - 128];
      acc = fmaf(W_in[d * 512 + j], v, acc);
    }
    Wfp[i] = acc;
    return;
  }
  i -= 4 * 512 * 192;
  if (i < 64) {
    float a = __expf(A_log[i]);
    Abar[i] = __expf(-a);
    Apow[i] = __expf(-a * (float)SCAN_L);
  }
}

// ---------------- prep_b: reduce partials, build Wcat2 / Wbig tail / bias_proj ----
// seg0 294912: Wcat2[n][k] (K=576): k<64 -> W1[k][n]; else D_skip*W_out
// seg1  98304: Wbig[512+n][d] = sum_s Wfp[s][d][n]
// seg2  32768: Wbig[704+n][d] = 0
// seg3    192: bias_proj[n] = b_in @ Wcat_col_n + {0|b_B|b_C}
__global__ __launch_bounds__(256) void prep_b(
    const float* __restrict__ W_out, const float* __restrict__ D_skip,
    const float* __restrict__ W1p, const float* __restrict__ Wfp,
    const float* __restrict__ b_in, const float* __restrict__ b_B,
    const float* __restrict__ b_C,
    const float* __restrict__ W_xs, const float* __restrict__ W_B_w,
    const float* __restrict__ W_C_w,
    bf16_t* __restrict__ Wcat2, bf16_t* __restrict__ Wbig,
    float* __restrict__ bias_proj) {
  int i = blockIdx.x * 256 + threadIdx.x;
  if (i < 512 * 576) {
    int n = i / 576, k = i - n * 576;
    float v;
    if (k < 64) {
      v = W1p[(0 * 64 + k) * 512 + n] + W1p[(1 * 64 + k) * 512 + n]
        + W1p[(2 * 64 + k) * 512 + n] + W1p[(3 * 64 + k) * 512 + n];
    } else {
      v = D_skip[k - 64] * W_out[(size_t)(k - 64) * 512 + n];
    }
    Wcat2[i] = f2bf(v);
    return;
  }
  i -= 512 * 576;
  if (i < 192 * 512) {
    int n = i >> 9, d = i & 511;
    float v = Wfp[(0 * 512 + d) * 192 + n] + Wfp[(1 * 512 + d) * 192 + n]
            + Wfp[(2 * 512 + d) * 192 + n] + Wfp[(3 * 512 + d) * 192 + n];
    Wbig[(size_t)(512 + n) * 512 + d] = f2bf(v);
    return;
  }
  i -= 192 * 512;
  if (i < 64 * 512) {
    int n = i >> 9, d = i & 511;
    Wbig[(size_t)(704 + n) * 512 + d] = 0;
    return;
  }
  i -= 64 * 512;
  if (i < 192) {
    float acc = 0.f;
    for (int d = 0; d < 512; ++d) {
      float v = (i < 64) ? W_xs[d * 64 + i]
              : (i < 128) ? W_B_w[d * 64 + i - 64] : W_C_w[d * 64 + i - 128];
      acc = fmaf(b_in[d], v, acc);
    }
    if (i >= 128)      acc += b_C[i - 128];
    else if (i >= 64)  acc += b_B[i - 64];
    bias_proj[i] = acc;
  }
}

// ---------------- LayerNorm: one wave per row, fp32 -> bf16 ----------------
__global__ __launch_bounds__(256) void ln_kernel(
    const float* __restrict__ x, const float* __restrict__ gamma,
    const float* __restrict__ beta, bf16_t* __restrict__ xn) {
  const int row = blockIdx.x * 4 + (threadIdx.x >> 6);
  const int lane = threadIdx.x & 63;
  const float* xr = x + (size_t)row * 512 + lane * 8;
  float4 v0 = *(const float4*)xr;
  float4 v1 = *(const float4*)(xr + 4);
  float s  = v0.x + v0.y + v0.z + v0.w + v1.x + v1.y + v1.z + v1.w;
  float sq = v0.x*v0.x + v0.y*v0.y + v0.z*v0.z + v0.w*v0.w
           + v1.x*v1.x + v1.y*v1.y + v1.z*v1.z + v1.w*v1.w;
  #pragma unroll
  for (int off = 32; off > 0; off >>= 1) {
    s  += __shfl_xor(s, off, 64);
    sq += __shfl_xor(sq, off, 64);
  }
  const float mu  = s * (1.0f / 512.0f);
  const float var = sq * (1.0f / 512.0f) - mu * mu;
  const float rs  = rsqrtf(var + 1e-3f);
  float4 g0 = *(const float4*)(gamma + lane * 8);
  float4 g1 = *(const float4*)(gamma + lane * 8 + 4);
  float4 b0 = *(const float4*)(beta + lane * 8);
  float4 b1 = *(const float4*)(beta + lane * 8 + 4);
  bh8 ov;
  ov[0] = (short)f2bf((v0.x - mu) * rs * g0.x + b0.x);
  ov[1] = (short)f2bf((v0.y - mu) * rs * g0.y + b0.y);
  ov[2] = (short)f2bf((v0.z - mu) * rs * g0.z + b0.z);
  ov[3] = (short)f2bf((v0.w - mu) * rs * g0.w + b0.w);
  ov[4] = (short)f2bf((v1.x - mu) * rs * g1.x + b1.x);
  ov[5] = (short)f2bf((v1.y - mu) * rs * g1.y + b1.y);
  ov[6] = (short)f2bf((v1.z - mu) * rs * g1.z + b1.z);
  ov[7] = (short)f2bf((v1.w - mu) * rs * g1.w + b1.w);
  *(bh8*)(xn + (size_t)row * 512 + lane * 8) = ov;
}

// ---------------- MFMA GEMM: 128x128 tile, BK=64, 4 waves of 64x64 ----------------
// MODE 2 (fused): [xp|proj] = xn @ Wbig^T; cols<512 -> xp bf16 (+b_in),
//                 cols 512..703 -> proj planar fp32 (+bias_proj), cols>=704 discard.
// MODE 3 (out):   out = [CH|xp] @ Wcat2^T + b_out + x   (K=576)
template <int MODE>
__global__ __launch_bounds__(256, 4) void gemm_mfma(
    const bf16_t* __restrict__ A0, const bf16_t* __restrict__ A1,
    const bf16_t* __restrict__ Wt, int K,
    bf16_t* __restrict__ outbf, float* __restrict__ outf,
    const float* __restrict__ bias0, const float* __restrict__ bias1,
    const float* __restrict__ resid) {
  __shared__ __align__(16) bf16_t As[128 * 64];
  __shared__ __align__(16) bf16_t Bs[128 * 64];
  const int tid = threadIdx.x;
  const int wave = tid >> 6, lane = tid & 63;
  const int quad = lane >> 4, l16 = lane & 15;
  const int wm = (wave >> 1) * 64, wn = (wave & 1) * 64;
  const int mb = blockIdx.x, nb = blockIdx.y;

  f4 acc[4][4];
  #pragma unroll
  for (int i = 0; i < 4; ++i)
    #pragma unroll
    for (int j = 0; j < 4; ++j) acc[i][j] = (f4){0.f, 0.f, 0.f, 0.f};

  const int nkt = K >> 6;
  for (int kt = 0; kt < nkt; ++kt) {
    const int k0 = kt << 6;
    const bf16_t* Ap; int lda, kk;
    if (MODE == 3) {
      if (kt == 0) { Ap = A0; lda = 64;  kk = 0; }        // CH tile (K 0..63)
      else         { Ap = A1; lda = 512; kk = k0 - 64; }  // xp tile
    } else { Ap = A0; lda = K; kk = k0; }

    __syncthreads();
    #pragma unroll
    for (int i = 0; i < 4; ++i) {
      const int base = (wave * 4 + i) * 64;
      const int cid = base + lane;
      const int row = cid >> 3;
      const int g = (cid & 7) ^ (row & 7);
      async_cp16((char*)As + base * 16,
                 Ap + (size_t)(mb * 128 + row) * lda + kk + g * 8);
    }
    #pragma unroll
    for (int i = 0; i < 4; ++i) {
      const int base = (wave * 4 + i) * 64;
      const int cid = base + lane;
      const int row = cid >> 3;
      const int g = (cid & 7) ^ (row & 7);
      async_cp16((char*)Bs + base * 16,
                 Wt + (size_t)(nb * 128 + row) * K + k0 + g * 8);
    }
    __syncthreads();

    #pragma unroll
    for (int ks = 0; ks < 2; ++ks) {
      const int gb = ks * 4 + quad;
      bh8 af[4], bfv[4];
      #pragma unroll
      for (int im = 0; im < 4; ++im) {
        const int row = wm + im * 16 + l16;
        af[im] = *(const bh8*)((const char*)As + row * 128 + ((gb ^ (row & 7)) * 16));
      }
      #pragma unroll
      for (int in_ = 0; in_ < 4; ++in_) {
        const int row = wn + in_ * 16 + l16;
        bfv[in_] = *(const bh8*)((const char*)Bs + row * 128 + ((gb ^ (row & 7)) * 16));
      }
      #pragma unroll
      for (int im = 0; im < 4; ++im)
        #pragma unroll
        for (int in_ = 0; in_ < 4; ++in_)
          acc[im][in_] = __builtin_amdgcn_mfma_f32_16x16x32_bf16(af[im], bfv[in_],
                                                                 acc[im][in_], 0, 0, 0);
    }
  }

  // epilogue: C/D layout col=lane&15, row=quad*4+reg
  #pragma unroll
  for (int im = 0; im < 4; ++im) {
    #pragma unroll
    for (int in_ = 0; in_ < 4; ++in_) {
      #pragma unroll
      for (int r = 0; r < 4; ++r) {
        const int row = mb * 128 + wm + im * 16 + quad * 4 + r;
        const int col = nb * 128 + wn + in_ * 16 + l16;
        float v = acc[im][in_][r];
        if (MODE == 2) {
          if (col < 512) {
            outbf[(size_t)row * 512 + col] = f2bf(v + bias0[col]);
          } else if (col < 704) {
            const int cc = col - 512;
            outf[((size_t)(cc >> 6) * M_ROWS + row) * 64 + (cc & 63)] = v + bias1[cc];
          }
        } else {
          outf[(size_t)row * 512 + col] = v + bias0[col] + resid[(size_t)row * 512 + col];
        }
      }
    }
  }
}

// ---------------- chunked scan: SCAN_C chunks x SCAN_L steps, 512 chains --------
__global__ __launch_bounds__(64) void scan_chunk(
    const float* __restrict__ projP, const float* __restrict__ Abar,
    float* __restrict__ carry) {
  const int b = blockIdx.x >> 7, c = blockIdx.x & (SCAN_C - 1), n = threadIdx.x;
  const float A = Abar[n];
  const size_t row0 = (size_t)b * 4096 + c * SCAN_L;
  const float* pxs = projP + row0 * 64;
  const float* pB  = projP + ((size_t)M_ROWS + row0) * 64;
  float h = 0.f;
  for (int i = 0; i < SCAN_L; ++i)
    h = fmaf(A, h, pxs[i * 64 + n] * pB[i * 64 + n]);
  carry[(b * SCAN_C + c) * 64 + n] = h;
}

__global__ __launch_bounds__(512) void scan_carry(
    const float* __restrict__ carry, const float* __restrict__ Apow,
    float* __restrict__ cin) {
  const int b = threadIdx.x >> 6, n = threadIdx.x & 63;
  const float Ap = Apow[n];
  float h = 0.f;
  for (int c = 0; c < SCAN_C; ++c) {
    cin[(b * SCAN_C + c) * 64 + n] = h;
    h = fmaf(Ap, h, carry[(b * SCAN_C + c) * 64 + n]);
  }
}

__global__ __launch_bounds__(64) void scan_apply(
    const float* __restrict__ projP, const float* __restrict__ Abar,
    const float* __restrict__ cin, bf16_t* __restrict__ CH) {
  const int b = blockIdx.x >> 7, c = blockIdx.x & (SCAN_C - 1), n = threadIdx.x;
  const float A = Abar[n];
  const size_t row0 = (size_t)b * 4096 + c * SCAN_L;
  const float* pxs = projP + row0 * 64;
  const float* pB  = projP + ((size_t)M_ROWS + row0) * 64;
  const float* pC  = projP + ((size_t)2 * M_ROWS + row0) * 64;
  bf16_t* o = CH + row0 * 64;
  float h = cin[(b * SCAN_C + c) * 64 + n];
  for (int i = 0; i < SCAN_L; ++i) {
    h = fmaf(A, h, pxs[i * 64 + n] * pB[i * 64 + n]);
    o[i * 64 + n] = f2bf(pC[i * 64 + n] * h);
  }
}

// ---------------- launch ----------------
extern "C" void kernel_launch(void* const* d_in, const int* in_sizes, int n_in,
                              void* d_out, int out_size, void* d_ws, size_t ws_size,
                              hipStream_t stream) {
  const float* x      = (const float*)d_in[0];
  const float* ln_g   = (const float*)d_in[1];
  const float* ln_b   = (const float*)d_in[2];
  const float* W_in   = (const float*)d_in[3];
  const float* b_in   = (const float*)d_in[4];
  const float* W_xs   = (const float*)d_in[5];
  const float* W_B    = (const float*)d_in[6];
  const float* b_B    = (const float*)d_in[7];
  const float* W_C    = (const float*)d_in[8];
  const float* b_C    = (const float*)d_in[9];
  const float* A_log  = (const float*)d_in[10];
  const float* D_skip = (const float*)d_in[11];
  const float* W_so   = (const float*)d_in[12];
  const float* W_out  = (const float*)d_in[13];
  const float* b_out  = (const float*)d_in[14];
  float* out = (float*)d_out;

  char* w = (char*)d_ws;
  auto carve = [&](size_t bytes) {
    char* p = w; w += (bytes + 255) & ~(size_t)255; return p;
  };
  bf16_t* xn     = (bf16_t*)carve((size_t)M_ROWS * 512 * 2);
  bf16_t* xp     = (bf16_t*)carve((size_t)M_ROWS * 512 * 2);
  float*  projP  = (float*)carve((size_t)3 * M_ROWS * 64 * 4);
  bf16_t* CH     = (bf16_t*)carve((size_t)M_ROWS * 64 * 2);
  float*  carry  = (float*)carve((size_t)8 * SCAN_C * 64 * 4);
  float*  cin    = (float*)carve((size_t)8 * SCAN_C * 64 * 4);
  bf16_t* Wbig   = (bf16_t*)carve((size_t)768 * 512 * 2);
  bf16_t* Wcat2  = (bf16_t*)carve((size_t)512 * 576 * 2);
  float*  W1p    = (float*)carve((size_t)4 * 64 * 512 * 4);
  float*  Wfp    = (float*)carve((size_t)4 * 512 * 192 * 4);
  float*  biasp  = (float*)carve(192 * 4);
  float*  Abar   = (float*)carve(256);
  float*  Apow   = (float*)carve(256);

  prep_a<<<3073, 256, 0, stream>>>(W_in, W_xs, W_B, W_C, W_so, W_out, A_log,
                                   Wbig, W1p, Wfp, Abar, Apow);
  prep_b<<<1665, 256, 0, stream>>>(W_out, D_skip, W1p, Wfp, b_in, b_B, b_C,
                                   W_xs, W_B, W_C, Wcat2, Wbig, biasp);
  ln_kernel<<<8192, 256, 0, stream>>>(x, ln_g, ln_b, xn);
  gemm_mfma<2><<<dim3(256, 6), 256, 0, stream>>>(xn, nullptr, Wbig, 512,
                                                 xp, projP, b_in, biasp, nullptr);
  scan_chunk<<<8 * SCAN_C, 64, 0, stream>>>(projP, Abar, carry);
  scan_carry<<<1, 512, 0, stream>>>(carry, Apow, cin);
  scan_apply<<<8 * SCAN_C, 64, 0, stream>>>(projP, Abar, cin, CH);
  gemm_mfma<3><<<dim3(256, 4), 256, 0, stream>>>(CH, xp, Wcat2, 576,
                                                 nullptr, out, b_out, nullptr, x);
}

// Round 3
// 309.197 us; speedup vs baseline: 1.0948x; 1.0948x over previous
//
#include <hip/hip_runtime.h>
#include <cstdint>
#include <cstddef>

// SSMLayer, round 3:
//   LN -> fused GEMM (xn @ [W_in | W_in@Wcat] -> xp bf16 + proj fp32 planar)
//      -> chunked parallel scan (L=32, 128 chunks) -> CH bf16
//      -> output GEMM  out = [CH|xp] @ [W_so@W_out | D.*W_out]^T + b_out + x
// Round-3 fix: prep kernels are read-coalesced everywhere (scatters moved to
// the store side), and the serial bias_proj tail is replaced by K-split
// partials + tiny reduce. No serial blocks anywhere in prep.

typedef unsigned short bf16_t;
typedef __attribute__((ext_vector_type(8))) short bh8;
typedef __attribute__((ext_vector_type(4))) float f4;

#define M_ROWS 32768
#define SCAN_L 32
#define SCAN_C 128   // 4096 / SCAN_L

__device__ __forceinline__ unsigned short f2bf(float f) {
  union { float f; unsigned int u; } c; c.f = f;
  unsigned int u = c.u;
  return (unsigned short)((u + 0x7FFFu + ((u >> 16) & 1u)) >> 16);
}

__device__ __forceinline__ void async_cp16(void* lds, const void* g) {
  __builtin_amdgcn_global_load_lds((const __attribute__((address_space(1))) void*)g,
                                   (__attribute__((address_space(3))) void*)lds, 16, 0, 0);
}

// ---------------- prep_a ----------------
// seg0 262144: Wbig[n][k] = W_in[k][n]      (read-coalesced: consec threads = consec n)
// seg1 131072: W1p[s][k][n]   partial W_so@W_out  (consec n; coalesced)
// seg2 393216: Wfp[s][n][d]   partial W_in@Wcat   (consec n reads; scattered writes)
// seg3   1536: bias_pp[s][n]  partial b_in@Wcat   (s = d-slice of 64)
// seg4     64: Abar = exp(-exp(A_log)), Apow = Abar^SCAN_L
__global__ __launch_bounds__(256) void prep_a(
    const float* __restrict__ W_in, const float* __restrict__ W_xs,
    const float* __restrict__ W_B,  const float* __restrict__ W_C,
    const float* __restrict__ W_so, const float* __restrict__ W_out,
    const float* __restrict__ A_log, const float* __restrict__ b_in,
    bf16_t* __restrict__ Wbig, float* __restrict__ W1p, float* __restrict__ Wfp,
    float* __restrict__ bias_pp, float* __restrict__ Abar, float* __restrict__ Apow) {
  int i = blockIdx.x * 256 + threadIdx.x;
  if (i < 512 * 512) {                       // transpose W_in (coalesced reads)
    int k = i >> 9, n = i & 511;
    Wbig[(size_t)n * 512 + k] = f2bf(W_in[k * 512 + n]);
    return;
  }
  i -= 512 * 512;
  if (i < 4 * 64 * 512) {                    // W1 partials, [s][k][n]
    int s = i >> 15, r = i & 32767, k = r >> 9, n = r & 511;
    float acc = 0.f;
    const int j0 = s * 128;
    for (int j = j0; j < j0 + 128; ++j)
      acc = fmaf(W_so[k * 512 + j], W_out[j * 512 + n], acc);
    W1p[i] = acc;
    return;
  }
  i -= 4 * 64 * 512;
  if (i < 4 * 512 * 192) {                   // Wfuse partials -> [s][n][d]
    int s = i / (512 * 192), r = i - s * 512 * 192, d = r / 192, n = r - d * 192;
    float acc = 0.f;
    const int j0 = s * 128;
    for (int j = j0; j < j0 + 128; ++j) {
      float v = (n < 64) ? W_xs[j * 64 + n]
              : (n < 128) ? W_B[j * 64 + n - 64] : W_C[j * 64 + n - 128];
      acc = fmaf(W_in[d * 512 + j], v, acc);
    }
    Wfp[((size_t)s * 192 + n) * 512 + d] = acc;   // scattered write (no stall)
    return;
  }
  i -= 4 * 512 * 192;
  if (i < 8 * 192) {                         // bias partials over d-slices of 64
    int s = i / 192, n = i - s * 192;
    float acc = 0.f;
    const int d0 = s * 64;
    for (int d = d0; d < d0 + 64; ++d) {
      float v = (n < 64) ? W_xs[d * 64 + n]
              : (n < 128) ? W_B[d * 64 + n - 64] : W_C[d * 64 + n - 128];
      acc = fmaf(b_in[d], v, acc);
    }
    bias_pp[s * 192 + n] = acc;
    return;
  }
  i -= 8 * 192;
  if (i < 64) {
    float a = __expf(A_log[i]);
    Abar[i] = __expf(-a);
    Apow[i] = __expf(-a * (float)SCAN_L);
  }
}

// ---------------- prep_b ----------------
// seg0 294912: Wcat2[n][k] (K=576): k<64 -> W1[k][n]; else D_skip*W_out
//              (consec threads = consec n: all reads coalesced, write scattered)
// seg1  98304: Wbig[512+n][d] = sum_s Wfp[s][n][d]   (fully coalesced)
// seg2  32768: Wbig[704+n][d] = 0
// seg3    192: bias_proj[n] = sum_s bias_pp[s][n] + {0|b_B|b_C}
__global__ __launch_bounds__(256) void prep_b(
    const float* __restrict__ W_out, const float* __restrict__ D_skip,
    const float* __restrict__ W1p, const float* __restrict__ Wfp,
    const float* __restrict__ bias_pp,
    const float* __restrict__ b_B, const float* __restrict__ b_C,
    bf16_t* __restrict__ Wcat2, bf16_t* __restrict__ Wbig,
    float* __restrict__ bias_proj) {
  int i = blockIdx.x * 256 + threadIdx.x;
  if (i < 576 * 512) {
    int k = i >> 9, n = i & 511;
    float v;
    if (k < 64) {
      v = W1p[(size_t)(0 * 64 + k) * 512 + n] + W1p[(size_t)(1 * 64 + k) * 512 + n]
        + W1p[(size_t)(2 * 64 + k) * 512 + n] + W1p[(size_t)(3 * 64 + k) * 512 + n];
    } else {
      v = D_skip[k - 64] * W_out[(size_t)(k - 64) * 512 + n];
    }
    Wcat2[(size_t)n * 576 + k] = f2bf(v);    // scattered write
    return;
  }
  i -= 576 * 512;
  if (i < 192 * 512) {
    int n = i >> 9, d = i & 511;
    float v = Wfp[((size_t)0 * 192 + n) * 512 + d] + Wfp[((size_t)1 * 192 + n) * 512 + d]
            + Wfp[((size_t)2 * 192 + n) * 512 + d] + Wfp[((size_t)3 * 192 + n) * 512 + d];
    Wbig[(size_t)(512 + n) * 512 + d] = f2bf(v);
    return;
  }
  i -= 192 * 512;
  if (i < 64 * 512) {
    int n = i >> 9, d = i & 511;
    Wbig[(size_t)(704 + n) * 512 + d] = 0;
    return;
  }
  i -= 64 * 512;
  if (i < 192) {
    float acc = 0.f;
    #pragma unroll
    for (int s = 0; s < 8; ++s) acc += bias_pp[s * 192 + i];
    if (i >= 128)      acc += b_C[i - 128];
    else if (i >= 64)  acc += b_B[i - 64];
    bias_proj[i] = acc;
  }
}

// ---------------- LayerNorm: one wave per row, fp32 -> bf16 ----------------
__global__ __launch_bounds__(256) void ln_kernel(
    const float* __restrict__ x, const float* __restrict__ gamma,
    const float* __restrict__ beta, bf16_t* __restrict__ xn) {
  const int row = blockIdx.x * 4 + (threadIdx.x >> 6);
  const int lane = threadIdx.x & 63;
  const float* xr = x + (size_t)row * 512 + lane * 8;
  float4 v0 = *(const float4*)xr;
  float4 v1 = *(const float4*)(xr + 4);
  float s  = v0.x + v0.y + v0.z + v0.w + v1.x + v1.y + v1.z + v1.w;
  float sq = v0.x*v0.x + v0.y*v0.y + v0.z*v0.z + v0.w*v0.w
           + v1.x*v1.x + v1.y*v1.y + v1.z*v1.z + v1.w*v1.w;
  #pragma unroll
  for (int off = 32; off > 0; off >>= 1) {
    s  += __shfl_xor(s, off, 64);
    sq += __shfl_xor(sq, off, 64);
  }
  const float mu  = s * (1.0f / 512.0f);
  const float var = sq * (1.0f / 512.0f) - mu * mu;
  const float rs  = rsqrtf(var + 1e-3f);
  float4 g0 = *(const float4*)(gamma + lane * 8);
  float4 g1 = *(const float4*)(gamma + lane * 8 + 4);
  float4 b0 = *(const float4*)(beta + lane * 8);
  float4 b1 = *(const float4*)(beta + lane * 8 + 4);
  bh8 ov;
  ov[0] = (short)f2bf((v0.x - mu) * rs * g0.x + b0.x);
  ov[1] = (short)f2bf((v0.y - mu) * rs * g0.y + b0.y);
  ov[2] = (short)f2bf((v0.z - mu) * rs * g0.z + b0.z);
  ov[3] = (short)f2bf((v0.w - mu) * rs * g0.w + b0.w);
  ov[4] = (short)f2bf((v1.x - mu) * rs * g1.x + b1.x);
  ov[5] = (short)f2bf((v1.y - mu) * rs * g1.y + b1.y);
  ov[6] = (short)f2bf((v1.z - mu) * rs * g1.z + b1.z);
  ov[7] = (short)f2bf((v1.w - mu) * rs * g1.w + b1.w);
  *(bh8*)(xn + (size_t)row * 512 + lane * 8) = ov;
}

// ---------------- MFMA GEMM: 128x128 tile, BK=64, 4 waves of 64x64 ----------------
// MODE 2 (fused): [xp|proj] = xn @ Wbig^T; cols<512 -> xp bf16 (+b_in),
//                 cols 512..703 -> proj planar fp32 (+bias_proj), cols>=704 discard.
// MODE 3 (out):   out = [CH|xp] @ Wcat2^T + b_out + x   (K=576)
template <int MODE>
__global__ __launch_bounds__(256, 4) void gemm_mfma(
    const bf16_t* __restrict__ A0, const bf16_t* __restrict__ A1,
    const bf16_t* __restrict__ Wt, int K,
    bf16_t* __restrict__ outbf, float* __restrict__ outf,
    const float* __restrict__ bias0, const float* __restrict__ bias1,
    const float* __restrict__ resid) {
  __shared__ __align__(16) bf16_t As[128 * 64];
  __shared__ __align__(16) bf16_t Bs[128 * 64];
  const int tid = threadIdx.x;
  const int wave = tid >> 6, lane = tid & 63;
  const int quad = lane >> 4, l16 = lane & 15;
  const int wm = (wave >> 1) * 64, wn = (wave & 1) * 64;
  const int mb = blockIdx.x, nb = blockIdx.y;

  f4 acc[4][4];
  #pragma unroll
  for (int i = 0; i < 4; ++i)
    #pragma unroll
    for (int j = 0; j < 4; ++j) acc[i][j] = (f4){0.f, 0.f, 0.f, 0.f};

  const int nkt = K >> 6;
  for (int kt = 0; kt < nkt; ++kt) {
    const int k0 = kt << 6;
    const bf16_t* Ap; int lda, kk;
    if (MODE == 3) {
      if (kt == 0) { Ap = A0; lda = 64;  kk = 0; }        // CH tile (K 0..63)
      else         { Ap = A1; lda = 512; kk = k0 - 64; }  // xp tile
    } else { Ap = A0; lda = K; kk = k0; }

    __syncthreads();
    #pragma unroll
    for (int i = 0; i < 4; ++i) {
      const int base = (wave * 4 + i) * 64;
      const int cid = base + lane;
      const int row = cid >> 3;
      const int g = (cid & 7) ^ (row & 7);
      async_cp16((char*)As + base * 16,
                 Ap + (size_t)(mb * 128 + row) * lda + kk + g * 8);
    }
    #pragma unroll
    for (int i = 0; i < 4; ++i) {
      const int base = (wave * 4 + i) * 64;
      const int cid = base + lane;
      const int row = cid >> 3;
      const int g = (cid & 7) ^ (row & 7);
      async_cp16((char*)Bs + base * 16,
                 Wt + (size_t)(nb * 128 + row) * K + k0 + g * 8);
    }
    __syncthreads();

    #pragma unroll
    for (int ks = 0; ks < 2; ++ks) {
      const int gb = ks * 4 + quad;
      bh8 af[4], bfv[4];
      #pragma unroll
      for (int im = 0; im < 4; ++im) {
        const int row = wm + im * 16 + l16;
        af[im] = *(const bh8*)((const char*)As + row * 128 + ((gb ^ (row & 7)) * 16));
      }
      #pragma unroll
      for (int in_ = 0; in_ < 4; ++in_) {
        const int row = wn + in_ * 16 + l16;
        bfv[in_] = *(const bh8*)((const char*)Bs + row * 128 + ((gb ^ (row & 7)) * 16));
      }
      #pragma unroll
      for (int im = 0; im < 4; ++im)
        #pragma unroll
        for (int in_ = 0; in_ < 4; ++in_)
          acc[im][in_] = __builtin_amdgcn_mfma_f32_16x16x32_bf16(af[im], bfv[in_],
                                                                 acc[im][in_], 0, 0, 0);
    }
  }

  // epilogue: C/D layout col=lane&15, row=quad*4+reg
  #pragma unroll
  for (int im = 0; im < 4; ++im) {
    #pragma unroll
    for (int in_ = 0; in_ < 4; ++in_) {
      #pragma unroll
      for (int r = 0; r < 4; ++r) {
        const int row = mb * 128 + wm + im * 16 + quad * 4 + r;
        const int col = nb * 128 + wn + in_ * 16 + l16;
        float v = acc[im][in_][r];
        if (MODE == 2) {
          if (col < 512) {
            outbf[(size_t)row * 512 + col] = f2bf(v + bias0[col]);
          } else if (col < 704) {
            const int cc = col - 512;
            outf[((size_t)(cc >> 6) * M_ROWS + row) * 64 + (cc & 63)] = v + bias1[cc];
          }
        } else {
          outf[(size_t)row * 512 + col] = v + bias0[col] + resid[(size_t)row * 512 + col];
        }
      }
    }
  }
}

// ---------------- chunked scan: SCAN_C chunks x SCAN_L steps, 512 chains --------
__global__ __launch_bounds__(64) void scan_chunk(
    const float* __restrict__ projP, const float* __restrict__ Abar,
    float* __restrict__ carry) {
  const int b = blockIdx.x >> 7, c = blockIdx.x & (SCAN_C - 1), n = threadIdx.x;
  const float A = Abar[n];
  const size_t row0 = (size_t)b * 4096 + c * SCAN_L;
  const float* pxs = projP + row0 * 64;
  const float* pB  = projP + ((size_t)M_ROWS + row0) * 64;
  float h = 0.f;
  for (int i = 0; i < SCAN_L; ++i)
    h = fmaf(A, h, pxs[i * 64 + n] * pB[i * 64 + n]);
  carry[(b * SCAN_C + c) * 64 + n] = h;
}

__global__ __launch_bounds__(512) void scan_carry(
    const float* __restrict__ carry, const float* __restrict__ Apow,
    float* __restrict__ cin) {
  const int b = threadIdx.x >> 6, n = threadIdx.x & 63;
  const float Ap = Apow[n];
  float h = 0.f;
  for (int c = 0; c < SCAN_C; ++c) {
    cin[(b * SCAN_C + c) * 64 + n] = h;
    h = fmaf(Ap, h, carry[(b * SCAN_C + c) * 64 + n]);
  }
}

__global__ __launch_bounds__(64) void scan_apply(
    const float* __restrict__ projP, const float* __restrict__ Abar,
    const float* __restrict__ cin, bf16_t* __restrict__ CH) {
  const int b = blockIdx.x >> 7, c = blockIdx.x & (SCAN_C - 1), n = threadIdx.x;
  const float A = Abar[n];
  const size_t row0 = (size_t)b * 4096 + c * SCAN_L;
  const float* pxs = projP + row0 * 64;
  const float* pB  = projP + ((size_t)M_ROWS + row0) * 64;
  const float* pC  = projP + ((size_t)2 * M_ROWS + row0) * 64;
  bf16_t* o = CH + row0 * 64;
  float h = cin[(b * SCAN_C + c) * 64 + n];
  for (int i = 0; i < SCAN_L; ++i) {
    h = fmaf(A, h, pxs[i * 64 + n] * pB[i * 64 + n]);
    o[i * 64 + n] = f2bf(pC[i * 64 + n] * h);
  }
}

// ---------------- launch ----------------
extern "C" void kernel_launch(void* const* d_in, const int* in_sizes, int n_in,
                              void* d_out, int out_size, void* d_ws, size_t ws_size,
                              hipStream_t stream) {
  const float* x      = (const float*)d_in[0];
  const float* ln_g   = (const float*)d_in[1];
  const float* ln_b   = (const float*)d_in[2];
  const float* W_in   = (const float*)d_in[3];
  const float* b_in   = (const float*)d_in[4];
  const float* W_xs   = (const float*)d_in[5];
  const float* W_B    = (const float*)d_in[6];
  const float* b_B    = (const float*)d_in[7];
  const float* W_C    = (const float*)d_in[8];
  const float* b_C    = (const float*)d_in[9];
  const float* A_log  = (const float*)d_in[10];
  const float* D_skip = (const float*)d_in[11];
  const float* W_so   = (const float*)d_in[12];
  const float* W_out  = (const float*)d_in[13];
  const float* b_out  = (const float*)d_in[14];
  float* out = (float*)d_out;

  char* w = (char*)d_ws;
  auto carve = [&](size_t bytes) {
    char* p = w; w += (bytes + 255) & ~(size_t)255; return p;
  };
  bf16_t* xn     = (bf16_t*)carve((size_t)M_ROWS * 512 * 2);
  bf16_t* xp     = (bf16_t*)carve((size_t)M_ROWS * 512 * 2);
  float*  projP  = (float*)carve((size_t)3 * M_ROWS * 64 * 4);
  bf16_t* CH     = (bf16_t*)carve((size_t)M_ROWS * 64 * 2);
  float*  carry  = (float*)carve((size_t)8 * SCAN_C * 64 * 4);
  float*  cin    = (float*)carve((size_t)8 * SCAN_C * 64 * 4);
  bf16_t* Wbig   = (bf16_t*)carve((size_t)768 * 512 * 2);
  bf16_t* Wcat2  = (bf16_t*)carve((size_t)512 * 576 * 2);
  float*  W1p    = (float*)carve((size_t)4 * 64 * 512 * 4);
  float*  Wfp    = (float*)carve((size_t)4 * 192 * 512 * 4);
  float*  biaspp = (float*)carve(8 * 192 * 4);
  float*  biasp  = (float*)carve(192 * 4);
  float*  Abar   = (float*)carve(256);
  float*  Apow   = (float*)carve(256);

  prep_a<<<3079, 256, 0, stream>>>(W_in, W_xs, W_B, W_C, W_so, W_out, A_log, b_in,
                                   Wbig, W1p, Wfp, biaspp, Abar, Apow);
  prep_b<<<1665, 256, 0, stream>>>(W_out, D_skip, W1p, Wfp, biaspp, b_B, b_C,
                                   Wcat2, Wbig, biasp);
  ln_kernel<<<8192, 256, 0, stream>>>(x, ln_g, ln_b, xn);
  gemm_mfma<2><<<dim3(256, 6), 256, 0, stream>>>(xn, nullptr, Wbig, 512,
                                                 xp, projP, b_in, biasp, nullptr);
  scan_chunk<<<8 * SCAN_C, 64, 0, stream>>>(projP, Abar, carry);
  scan_carry<<<1, 512, 0, stream>>>(carry, Apow, cin);
  scan_apply<<<8 * SCAN_C, 64, 0, stream>>>(projP, Abar, cin, CH);
  gemm_mfma<3><<<dim3(256, 4), 256, 0, stream>>>(CH, xp, Wcat2, 576,
                                                 nullptr, out, b_out, nullptr, x);
}

// Round 4
// 267.700 us; speedup vs baseline: 1.2645x; 1.1550x over previous
//
#include <hip/hip_runtime.h>
#include <cstdint>
#include <cstddef>

// SSMLayer, round 4:
//   prep_all (loop-free transposes/casts) -> gemm_prep (MFMA: W_so@W_out and
//   [W_in;b_in]@Wcat, epilogue-scattered into Wcat2/Wbig/bias) -> LN ->
//   fused GEMM (xn @ [W_in | W_in@Wcat] -> xp bf16 + proj fp32 planar) ->
//   chunked scan -> output GEMM  out = [CH|xp] @ [W_so@W_out | D.*W_out]^T + b_out + x
// Round-4 fix: prep matmuls moved from serial VALU loops (58 us tail, 20%
// VALUBusy) onto MFMA. No per-thread K-loops anywhere in prep.

typedef unsigned short bf16_t;
typedef __attribute__((ext_vector_type(8))) short bh8;
typedef __attribute__((ext_vector_type(4))) float f4;

#define M_ROWS 32768
#define SCAN_L 32
#define SCAN_C 128   // 4096 / SCAN_L

__device__ __forceinline__ unsigned short f2bf(float f) {
  union { float f; unsigned int u; } c; c.f = f;
  unsigned int u = c.u;
  return (unsigned short)((u + 0x7FFFu + ((u >> 16) & 1u)) >> 16);
}

__device__ __forceinline__ uint2 pack4bf(f4 a) {
  uint2 r;
  r.x = (unsigned)f2bf(a[0]) | ((unsigned)f2bf(a[1]) << 16);
  r.y = (unsigned)f2bf(a[2]) | ((unsigned)f2bf(a[3]) << 16);
  return r;
}

__device__ __forceinline__ void async_cp16(void* lds, const void* g) {
  __builtin_amdgcn_global_load_lds((const __attribute__((address_space(1))) void*)g,
                                   (__attribute__((address_space(3))) void*)lds, 16, 0, 0);
}

// ---------------- prep_all: loop-free casts/transposes/zeros ----------------
// s0 262144: Wbig[n][k]   = bf16(W_in[k][n])
// s1 262144: Wout_t[n][k] = bf16(W_out[k][n])
// s2 262144: Win_b[d][j]  = bf16(W_in[d][j])           (straight cast)
// s3  65536: Win_b[512+r][j] = r==0 ? bf16(b_in[j]) : 0
// s4  65536: Wso_b[k][j]  = k<64 ? bf16(W_so[k][j]) : 0
// s5 131072: Wcat_t[n][k] = bf16({W_xs|W_B|W_C}[k][n]), n>=192 -> 0
// s6 262144: Wcat2[n][64+k2] = bf16(D_skip[k2]*W_out[k2][n])
// s7  32768: Wbig[704+r][d] = 0
// s8     64: Abar, Apow
__global__ __launch_bounds__(256) void prep_all(
    const float* __restrict__ W_in, const float* __restrict__ W_out,
    const float* __restrict__ W_so, const float* __restrict__ W_xs,
    const float* __restrict__ W_B,  const float* __restrict__ W_C,
    const float* __restrict__ b_in, const float* __restrict__ D_skip,
    const float* __restrict__ A_log,
    bf16_t* __restrict__ Wbig, bf16_t* __restrict__ Wout_t,
    bf16_t* __restrict__ Win_b, bf16_t* __restrict__ Wso_b,
    bf16_t* __restrict__ Wcat_t, bf16_t* __restrict__ Wcat2,
    float* __restrict__ Abar, float* __restrict__ Apow) {
  int i = blockIdx.x * 256 + threadIdx.x;
  if (i < 262144) { int k = i >> 9, n = i & 511;
    Wbig[(size_t)n * 512 + k] = f2bf(W_in[k * 512 + n]); return; }
  i -= 262144;
  if (i < 262144) { int k = i >> 9, n = i & 511;
    Wout_t[(size_t)n * 512 + k] = f2bf(W_out[k * 512 + n]); return; }
  i -= 262144;
  if (i < 262144) { Win_b[i] = f2bf(W_in[i]); return; }
  i -= 262144;
  if (i < 65536) { int r = i >> 9, j = i & 511;
    Win_b[(size_t)(512 + r) * 512 + j] = (r == 0) ? f2bf(b_in[j]) : (bf16_t)0; return; }
  i -= 65536;
  if (i < 65536) { int k = i >> 9, j = i & 511;
    Wso_b[i] = (k < 64) ? f2bf(W_so[k * 512 + j]) : (bf16_t)0; return; }
  i -= 65536;
  if (i < 131072) { int k = i >> 8, n = i & 255;
    float v = 0.f;
    if (n < 64)       v = W_xs[k * 64 + n];
    else if (n < 128) v = W_B[k * 64 + n - 64];
    else if (n < 192) v = W_C[k * 64 + n - 128];
    Wcat_t[(size_t)n * 512 + k] = f2bf(v); return; }
  i -= 131072;
  if (i < 262144) { int k2 = i >> 9, n = i & 511;
    Wcat2[(size_t)n * 576 + 64 + k2] = f2bf(D_skip[k2] * W_out[(size_t)k2 * 512 + n]);
    return; }
  i -= 262144;
  if (i < 32768) { int r = i >> 9, d = i & 511;
    Wbig[(size_t)(704 + r) * 512 + d] = 0; return; }
  i -= 32768;
  if (i < 64) {
    float a = __expf(A_log[i]);
    Abar[i] = __expf(-a);
    Apow[i] = __expf(-a * (float)SCAN_L);
  }
}

// ---------------- gemm_prep: two tiny MFMA GEMMs in one launch (14 blocks) ----
// roleF (bx 0..9):  C = Win_b(640x512) @ Wcat_t^T(256x512); mb=bx/2, nb=bx&1
//    row<512,col<192 -> Wbig[(512+col)][row..row+3] (transposed, 8B packed)
//    row==512,col<192 -> biasp[col] = v + {0|b_B|b_C}
// roleW (bx 10..13): C = Wso_b(128x512) @ Wout_t^T(512x512); nb=bx-10
//    row<64 -> Wcat2[col][row..row+3] (8B packed)
__global__ __launch_bounds__(256, 4) void gemm_prep(
    const bf16_t* __restrict__ Win_b, const bf16_t* __restrict__ Wcat_t,
    const bf16_t* __restrict__ Wso_b, const bf16_t* __restrict__ Wout_t,
    const float* __restrict__ b_B, const float* __restrict__ b_C,
    bf16_t* __restrict__ Wbig, bf16_t* __restrict__ Wcat2,
    float* __restrict__ biasp) {
  __shared__ __align__(16) bf16_t As[128 * 64];
  __shared__ __align__(16) bf16_t Bs[128 * 64];
  const int tid = threadIdx.x;
  const int wave = tid >> 6, lane = tid & 63;
  const int quad = lane >> 4, l16 = lane & 15;
  const int wm = (wave >> 1) * 64, wn = (wave & 1) * 64;
  const bool roleW = (blockIdx.x >= 10);
  const int mb = roleW ? 0 : (blockIdx.x >> 1);
  const int nb = roleW ? (blockIdx.x - 10) : (blockIdx.x & 1);
  const bf16_t* Ap = roleW ? Wso_b : Win_b;
  const bf16_t* Bp = roleW ? Wout_t : Wcat_t;

  f4 acc[4][4];
  #pragma unroll
  for (int i = 0; i < 4; ++i)
    #pragma unroll
    for (int j = 0; j < 4; ++j) acc[i][j] = (f4){0.f, 0.f, 0.f, 0.f};

  for (int kt = 0; kt < 8; ++kt) {
    const int k0 = kt << 6;
    __syncthreads();
    #pragma unroll
    for (int i = 0; i < 4; ++i) {
      const int base = (wave * 4 + i) * 64;
      const int cid = base + lane;
      const int row = cid >> 3;
      const int g = (cid & 7) ^ (row & 7);
      async_cp16((char*)As + base * 16,
                 Ap + (size_t)(mb * 128 + row) * 512 + k0 + g * 8);
    }
    #pragma unroll
    for (int i = 0; i < 4; ++i) {
      const int base = (wave * 4 + i) * 64;
      const int cid = base + lane;
      const int row = cid >> 3;
      const int g = (cid & 7) ^ (row & 7);
      async_cp16((char*)Bs + base * 16,
                 Bp + (size_t)(nb * 128 + row) * 512 + k0 + g * 8);
    }
    __syncthreads();
    #pragma unroll
    for (int ks = 0; ks < 2; ++ks) {
      const int gb = ks * 4 + quad;
      bh8 af[4], bfv[4];
      #pragma unroll
      for (int im = 0; im < 4; ++im) {
        const int row = wm + im * 16 + l16;
        af[im] = *(const bh8*)((const char*)As + row * 128 + ((gb ^ (row & 7)) * 16));
      }
      #pragma unroll
      for (int in_ = 0; in_ < 4; ++in_) {
        const int row = wn + in_ * 16 + l16;
        bfv[in_] = *(const bh8*)((const char*)Bs + row * 128 + ((gb ^ (row & 7)) * 16));
      }
      #pragma unroll
      for (int im = 0; im < 4; ++im)
        #pragma unroll
        for (int in_ = 0; in_ < 4; ++in_)
          acc[im][in_] = __builtin_amdgcn_mfma_f32_16x16x32_bf16(af[im], bfv[in_],
                                                                 acc[im][in_], 0, 0, 0);
    }
  }

  #pragma unroll
  for (int im = 0; im < 4; ++im) {
    #pragma unroll
    for (int in_ = 0; in_ < 4; ++in_) {
      const int row0 = mb * 128 + wm + im * 16 + quad * 4;
      const int col = nb * 128 + wn + in_ * 16 + l16;
      if (roleW) {
        if (row0 < 64)
          *(uint2*)(Wcat2 + (size_t)col * 576 + row0) = pack4bf(acc[im][in_]);
      } else if (col < 192) {
        if (row0 < 512) {
          *(uint2*)(Wbig + (size_t)(512 + col) * 512 + row0) = pack4bf(acc[im][in_]);
        } else if (row0 == 512) {
          float v = acc[im][in_][0];
          if (col >= 128)     v += b_C[col - 128];
          else if (col >= 64) v += b_B[col - 64];
          biasp[col] = v;
        }
      }
    }
  }
}

// ---------------- LayerNorm: one wave per row, fp32 -> bf16 ----------------
__global__ __launch_bounds__(256) void ln_kernel(
    const float* __restrict__ x, const float* __restrict__ gamma,
    const float* __restrict__ beta, bf16_t* __restrict__ xn) {
  const int row = blockIdx.x * 4 + (threadIdx.x >> 6);
  const int lane = threadIdx.x & 63;
  const float* xr = x + (size_t)row * 512 + lane * 8;
  float4 v0 = *(const float4*)xr;
  float4 v1 = *(const float4*)(xr + 4);
  float s  = v0.x + v0.y + v0.z + v0.w + v1.x + v1.y + v1.z + v1.w;
  float sq = v0.x*v0.x + v0.y*v0.y + v0.z*v0.z + v0.w*v0.w
           + v1.x*v1.x + v1.y*v1.y + v1.z*v1.z + v1.w*v1.w;
  #pragma unroll
  for (int off = 32; off > 0; off >>= 1) {
    s  += __shfl_xor(s, off, 64);
    sq += __shfl_xor(sq, off, 64);
  }
  const float mu  = s * (1.0f / 512.0f);
  const float var = sq * (1.0f / 512.0f) - mu * mu;
  const float rs  = rsqrtf(var + 1e-3f);
  float4 g0 = *(const float4*)(gamma + lane * 8);
  float4 g1 = *(const float4*)(gamma + lane * 8 + 4);
  float4 b0 = *(const float4*)(beta + lane * 8);
  float4 b1 = *(const float4*)(beta + lane * 8 + 4);
  bh8 ov;
  ov[0] = (short)f2bf((v0.x - mu) * rs * g0.x + b0.x);
  ov[1] = (short)f2bf((v0.y - mu) * rs * g0.y + b0.y);
  ov[2] = (short)f2bf((v0.z - mu) * rs * g0.z + b0.z);
  ov[3] = (short)f2bf((v0.w - mu) * rs * g0.w + b0.w);
  ov[4] = (short)f2bf((v1.x - mu) * rs * g1.x + b1.x);
  ov[5] = (short)f2bf((v1.y - mu) * rs * g1.y + b1.y);
  ov[6] = (short)f2bf((v1.z - mu) * rs * g1.z + b1.z);
  ov[7] = (short)f2bf((v1.w - mu) * rs * g1.w + b1.w);
  *(bh8*)(xn + (size_t)row * 512 + lane * 8) = ov;
}

// ---------------- MFMA GEMM: 128x128 tile, BK=64, 4 waves of 64x64 ----------------
// MODE 2 (fused): [xp|proj] = xn @ Wbig^T; cols<512 -> xp bf16 (+b_in),
//                 cols 512..703 -> proj planar fp32 (+bias_proj), cols>=704 discard.
// MODE 3 (out):   out = [CH|xp] @ Wcat2^T + b_out + x   (K=576)
template <int MODE>
__global__ __launch_bounds__(256, 4) void gemm_mfma(
    const bf16_t* __restrict__ A0, const bf16_t* __restrict__ A1,
    const bf16_t* __restrict__ Wt, int K,
    bf16_t* __restrict__ outbf, float* __restrict__ outf,
    const float* __restrict__ bias0, const float* __restrict__ bias1,
    const float* __restrict__ resid) {
  __shared__ __align__(16) bf16_t As[128 * 64];
  __shared__ __align__(16) bf16_t Bs[128 * 64];
  const int tid = threadIdx.x;
  const int wave = tid >> 6, lane = tid & 63;
  const int quad = lane >> 4, l16 = lane & 15;
  const int wm = (wave >> 1) * 64, wn = (wave & 1) * 64;
  const int mb = blockIdx.x, nb = blockIdx.y;

  f4 acc[4][4];
  #pragma unroll
  for (int i = 0; i < 4; ++i)
    #pragma unroll
    for (int j = 0; j < 4; ++j) acc[i][j] = (f4){0.f, 0.f, 0.f, 0.f};

  const int nkt = K >> 6;
  for (int kt = 0; kt < nkt; ++kt) {
    const int k0 = kt << 6;
    const bf16_t* Ap; int lda, kk;
    if (MODE == 3) {
      if (kt == 0) { Ap = A0; lda = 64;  kk = 0; }        // CH tile (K 0..63)
      else         { Ap = A1; lda = 512; kk = k0 - 64; }  // xp tile
    } else { Ap = A0; lda = K; kk = k0; }

    __syncthreads();
    #pragma unroll
    for (int i = 0; i < 4; ++i) {
      const int base = (wave * 4 + i) * 64;
      const int cid = base + lane;
      const int row = cid >> 3;
      const int g = (cid & 7) ^ (row & 7);
      async_cp16((char*)As + base * 16,
                 Ap + (size_t)(mb * 128 + row) * lda + kk + g * 8);
    }
    #pragma unroll
    for (int i = 0; i < 4; ++i) {
      const int base = (wave * 4 + i) * 64;
      const int cid = base + lane;
      const int row = cid >> 3;
      const int g = (cid & 7) ^ (row & 7);
      async_cp16((char*)Bs + base * 16,
                 Wt + (size_t)(nb * 128 + row) * K + k0 + g * 8);
    }
    __syncthreads();

    #pragma unroll
    for (int ks = 0; ks < 2; ++ks) {
      const int gb = ks * 4 + quad;
      bh8 af[4], bfv[4];
      #pragma unroll
      for (int im = 0; im < 4; ++im) {
        const int row = wm + im * 16 + l16;
        af[im] = *(const bh8*)((const char*)As + row * 128 + ((gb ^ (row & 7)) * 16));
      }
      #pragma unroll
      for (int in_ = 0; in_ < 4; ++in_) {
        const int row = wn + in_ * 16 + l16;
        bfv[in_] = *(const bh8*)((const char*)Bs + row * 128 + ((gb ^ (row & 7)) * 16));
      }
      #pragma unroll
      for (int im = 0; im < 4; ++im)
        #pragma unroll
        for (int in_ = 0; in_ < 4; ++in_)
          acc[im][in_] = __builtin_amdgcn_mfma_f32_16x16x32_bf16(af[im], bfv[in_],
                                                                 acc[im][in_], 0, 0, 0);
    }
  }

  // epilogue: C/D layout col=lane&15, row=quad*4+reg
  #pragma unroll
  for (int im = 0; im < 4; ++im) {
    #pragma unroll
    for (int in_ = 0; in_ < 4; ++in_) {
      #pragma unroll
      for (int r = 0; r < 4; ++r) {
        const int row = mb * 128 + wm + im * 16 + quad * 4 + r;
        const int col = nb * 128 + wn + in_ * 16 + l16;
        float v = acc[im][in_][r];
        if (MODE == 2) {
          if (col < 512) {
            outbf[(size_t)row * 512 + col] = f2bf(v + bias0[col]);
          } else if (col < 704) {
            const int cc = col - 512;
            outf[((size_t)(cc >> 6) * M_ROWS + row) * 64 + (cc & 63)] = v + bias1[cc];
          }
        } else {
          outf[(size_t)row * 512 + col] = v + bias0[col] + resid[(size_t)row * 512 + col];
        }
      }
    }
  }
}

// ---------------- chunked scan: SCAN_C chunks x SCAN_L steps, 512 chains --------
__global__ __launch_bounds__(64) void scan_chunk(
    const float* __restrict__ projP, const float* __restrict__ Abar,
    float* __restrict__ carry) {
  const int b = blockIdx.x >> 7, c = blockIdx.x & (SCAN_C - 1), n = threadIdx.x;
  const float A = Abar[n];
  const size_t row0 = (size_t)b * 4096 + c * SCAN_L;
  const float* pxs = projP + row0 * 64;
  const float* pB  = projP + ((size_t)M_ROWS + row0) * 64;
  float h = 0.f;
  for (int i = 0; i < SCAN_L; ++i)
    h = fmaf(A, h, pxs[i * 64 + n] * pB[i * 64 + n]);
  carry[(b * SCAN_C + c) * 64 + n] = h;
}

__global__ __launch_bounds__(512) void scan_carry(
    const float* __restrict__ carry, const float* __restrict__ Apow,
    float* __restrict__ cin) {
  const int b = threadIdx.x >> 6, n = threadIdx.x & 63;
  const float Ap = Apow[n];
  float h = 0.f;
  for (int c = 0; c < SCAN_C; ++c) {
    cin[(b * SCAN_C + c) * 64 + n] = h;
    h = fmaf(Ap, h, carry[(b * SCAN_C + c) * 64 + n]);
  }
}

__global__ __launch_bounds__(64) void scan_apply(
    const float* __restrict__ projP, const float* __restrict__ Abar,
    const float* __restrict__ cin, bf16_t* __restrict__ CH) {
  const int b = blockIdx.x >> 7, c = blockIdx.x & (SCAN_C - 1), n = threadIdx.x;
  const float A = Abar[n];
  const size_t row0 = (size_t)b * 4096 + c * SCAN_L;
  const float* pxs = projP + row0 * 64;
  const float* pB  = projP + ((size_t)M_ROWS + row0) * 64;
  const float* pC  = projP + ((size_t)2 * M_ROWS + row0) * 64;
  bf16_t* o = CH + row0 * 64;
  float h = cin[(b * SCAN_C + c) * 64 + n];
  for (int i = 0; i < SCAN_L; ++i) {
    h = fmaf(A, h, pxs[i * 64 + n] * pB[i * 64 + n]);
    o[i * 64 + n] = f2bf(pC[i * 64 + n] * h);
  }
}

// ---------------- launch ----------------
extern "C" void kernel_launch(void* const* d_in, const int* in_sizes, int n_in,
                              void* d_out, int out_size, void* d_ws, size_t ws_size,
                              hipStream_t stream) {
  const float* x      = (const float*)d_in[0];
  const float* ln_g   = (const float*)d_in[1];
  const float* ln_b   = (const float*)d_in[2];
  const float* W_in   = (const float*)d_in[3];
  const float* b_in   = (const float*)d_in[4];
  const float* W_xs   = (const float*)d_in[5];
  const float* W_B    = (const float*)d_in[6];
  const float* b_B    = (const float*)d_in[7];
  const float* W_C    = (const float*)d_in[8];
  const float* b_C    = (const float*)d_in[9];
  const float* A_log  = (const float*)d_in[10];
  const float* D_skip = (const float*)d_in[11];
  const float* W_so   = (const float*)d_in[12];
  const float* W_out  = (const float*)d_in[13];
  const float* b_out  = (const float*)d_in[14];
  float* out = (float*)d_out;

  char* w = (char*)d_ws;
  auto carve = [&](size_t bytes) {
    char* p = w; w += (bytes + 255) & ~(size_t)255; return p;
  };
  bf16_t* xn     = (bf16_t*)carve((size_t)M_ROWS * 512 * 2);
  bf16_t* xp     = (bf16_t*)carve((size_t)M_ROWS * 512 * 2);
  float*  projP  = (float*)carve((size_t)3 * M_ROWS * 64 * 4);
  bf16_t* CH     = (bf16_t*)carve((size_t)M_ROWS * 64 * 2);
  float*  carry  = (float*)carve((size_t)8 * SCAN_C * 64 * 4);
  float*  cin    = (float*)carve((size_t)8 * SCAN_C * 64 * 4);
  bf16_t* Wbig   = (bf16_t*)carve((size_t)768 * 512 * 2);
  bf16_t* Wcat2  = (bf16_t*)carve((size_t)512 * 576 * 2);
  bf16_t* Win_b  = (bf16_t*)carve((size_t)640 * 512 * 2);
  bf16_t* Wso_b  = (bf16_t*)carve((size_t)128 * 512 * 2);
  bf16_t* Wout_t = (bf16_t*)carve((size_t)512 * 512 * 2);
  bf16_t* Wcat_t = (bf16_t*)carve((size_t)256 * 512 * 2);
  float*  biasp  = (float*)carve(192 * 4);
  float*  Abar   = (float*)carve(256);
  float*  Apow   = (float*)carve(256);

  prep_all<<<5249, 256, 0, stream>>>(W_in, W_out, W_so, W_xs, W_B, W_C, b_in,
                                     D_skip, A_log, Wbig, Wout_t, Win_b, Wso_b,
                                     Wcat_t, Wcat2, Abar, Apow);
  gemm_prep<<<14, 256, 0, stream>>>(Win_b, Wcat_t, Wso_b, Wout_t, b_B, b_C,
                                    Wbig, Wcat2, biasp);
  ln_kernel<<<8192, 256, 0, stream>>>(x, ln_g, ln_b, xn);
  gemm_mfma<2><<<dim3(256, 6), 256, 0, stream>>>(xn, nullptr, Wbig, 512,
                                                 xp, projP, b_in, biasp, nullptr);
  scan_chunk<<<8 * SCAN_C, 64, 0, stream>>>(projP, Abar, carry);
  scan_carry<<<1, 512, 0, stream>>>(carry, Apow, cin);
  scan_apply<<<8 * SCAN_C, 64, 0, stream>>>(projP, Abar, cin, CH);
  gemm_mfma<3><<<dim3(256, 4), 256, 0, stream>>>(CH, xp, Wcat2, 576,
                                                 nullptr, out, b_out, nullptr, x);
}

// Round 5
// 238.467 us; speedup vs baseline: 1.4196x; 1.1226x over previous
//
#include <hip/hip_runtime.h>
#include <cstdint>
#include <cstddef>

// SSMLayer, round 5:
//   prep_all (casts/transposes) -> gemm_prep (MFMA: W1=W_so@W_out,
//   Wfuse=[W_in;b_in]@Wcat, W2=[W_in;b_in]@(D.*W_out)) -> LN -> proj GEMM
//   (xn @ Wfuse^T -> projP fp32 planar) -> chunked scan (2 kernels; carry-in
//   recomputed per block from chain-major carries) -> output GEMM
//   out = [CH|xn] @ [W1 | W2]^T + (b_out + b_in@D.*W_out) + x
// Round-5: xp eliminated entirely via the W2 fold; scan_carry kernel removed.

typedef unsigned short bf16_t;
typedef __attribute__((ext_vector_type(8))) short bh8;
typedef __attribute__((ext_vector_type(4))) float f4;

#define M_ROWS 32768
#define SCAN_L 32
#define SCAN_C 128   // 4096 / SCAN_L

__device__ __forceinline__ unsigned short f2bf(float f) {
  union { float f; unsigned int u; } c; c.f = f;
  unsigned int u = c.u;
  return (unsigned short)((u + 0x7FFFu + ((u >> 16) & 1u)) >> 16);
}

__device__ __forceinline__ uint2 pack4bf(f4 a) {
  uint2 r;
  r.x = (unsigned)f2bf(a[0]) | ((unsigned)f2bf(a[1]) << 16);
  r.y = (unsigned)f2bf(a[2]) | ((unsigned)f2bf(a[3]) << 16);
  return r;
}

__device__ __forceinline__ void async_cp16(void* lds, const void* g) {
  __builtin_amdgcn_global_load_lds((const __attribute__((address_space(1))) void*)g,
                                   (__attribute__((address_space(3))) void*)lds, 16, 0, 0);
}

// ---------------- prep_all: loop-free casts/transposes/zeros ----------------
// s0 262144: Wout_t[n][k]  = bf16(W_out[k][n])
// s1 262144: Wdout_t[n][k] = bf16(D_skip[k]*W_out[k][n])
// s2 262144: Win_b[d][j]   = bf16(W_in[d][j])
// s3  65536: Win_b[512+r][j] = r==0 ? bf16(b_in[j]) : 0   (rows 512..639)
// s4  65536: Wso_b[k][j]   = k<64 ? bf16(W_so[k][j]) : 0  (rows 0..127)
// s5 131072: Wcat_t[n][k]  = bf16({W_xs|W_B|W_C}[k][n]), n>=192 -> 0
// s6  32768: Wproj[192+r][d] = 0                          (pad rows 192..255)
// s7     64: Abar = exp(-exp(A_log)), Apow = Abar^SCAN_L
__global__ __launch_bounds__(256) void prep_all(
    const float* __restrict__ W_in, const float* __restrict__ W_out,
    const float* __restrict__ W_so, const float* __restrict__ W_xs,
    const float* __restrict__ W_B,  const float* __restrict__ W_C,
    const float* __restrict__ b_in, const float* __restrict__ D_skip,
    const float* __restrict__ A_log,
    bf16_t* __restrict__ Wout_t, bf16_t* __restrict__ Wdout_t,
    bf16_t* __restrict__ Win_b, bf16_t* __restrict__ Wso_b,
    bf16_t* __restrict__ Wcat_t, bf16_t* __restrict__ Wproj,
    float* __restrict__ Abar, float* __restrict__ Apow) {
  int i = blockIdx.x * 256 + threadIdx.x;
  if (i < 262144) { int k = i >> 9, n = i & 511;
    Wout_t[(size_t)n * 512 + k] = f2bf(W_out[k * 512 + n]); return; }
  i -= 262144;
  if (i < 262144) { int k = i >> 9, n = i & 511;
    Wdout_t[(size_t)n * 512 + k] = f2bf(D_skip[k] * W_out[k * 512 + n]); return; }
  i -= 262144;
  if (i < 262144) { Win_b[i] = f2bf(W_in[i]); return; }
  i -= 262144;
  if (i < 65536) { int r = i >> 9, j = i & 511;
    Win_b[(size_t)(512 + r) * 512 + j] = (r == 0) ? f2bf(b_in[j]) : (bf16_t)0; return; }
  i -= 65536;
  if (i < 65536) { int k = i >> 9, j = i & 511;
    Wso_b[i] = (k < 64) ? f2bf(W_so[k * 512 + j]) : (bf16_t)0; return; }
  i -= 65536;
  if (i < 131072) { int k = i >> 8, n = i & 255;
    float v = 0.f;
    if (n < 64)       v = W_xs[k * 64 + n];
    else if (n < 128) v = W_B[k * 64 + n - 64];
    else if (n < 192) v = W_C[k * 64 + n - 128];
    Wcat_t[(size_t)n * 512 + k] = f2bf(v); return; }
  i -= 131072;
  if (i < 32768) { int r = i >> 9, d = i & 511;
    Wproj[(size_t)(192 + r) * 512 + d] = 0; return; }
  i -= 32768;
  if (i < 64) {
    float a = __expf(A_log[i]);
    Abar[i] = __expf(-a);
    Apow[i] = __expf(-a * (float)SCAN_L);
  }
}

// ---------------- gemm_prep: three small MFMA GEMMs in one launch (34 blocks) ----
// roleF  (bx 0..9):   C = Win_b(640x512) @ Wcat_t^T(256x512)
//    row<512,col<192 -> Wproj[col][row..row+3] (8B packed)
//    row==512,col<192 -> biasp[col] = v + {0|b_B|b_C}
// roleW1 (bx 10..13): C = Wso_b(128x512) @ Wout_t^T(512x512)
//    row<64 -> Wcat2[col][row..row+3]
// roleW2 (bx 14..33): C = Win_b(640x512) @ Wdout_t^T(512x512)
//    row<512 -> Wcat2[col][64+row..64+row+3];  row==512 -> biasW2[col]
__global__ __launch_bounds__(256, 4) void gemm_prep(
    const bf16_t* __restrict__ Win_b, const bf16_t* __restrict__ Wcat_t,
    const bf16_t* __restrict__ Wso_b, const bf16_t* __restrict__ Wout_t,
    const bf16_t* __restrict__ Wdout_t,
    const float* __restrict__ b_B, const float* __restrict__ b_C,
    bf16_t* __restrict__ Wproj, bf16_t* __restrict__ Wcat2,
    float* __restrict__ biasp, float* __restrict__ biasW2) {
  __shared__ __align__(16) bf16_t As[128 * 64];
  __shared__ __align__(16) bf16_t Bs[128 * 64];
  const int tid = threadIdx.x;
  const int wave = tid >> 6, lane = tid & 63;
  const int quad = lane >> 4, l16 = lane & 15;
  const int wm = (wave >> 1) * 64, wn = (wave & 1) * 64;
  int role, mb, nb;
  if (blockIdx.x < 10)      { role = 0; mb = blockIdx.x >> 1; nb = blockIdx.x & 1; }
  else if (blockIdx.x < 14) { role = 1; mb = 0; nb = blockIdx.x - 10; }
  else { role = 2; int t = blockIdx.x - 14; mb = t >> 2; nb = t & 3; }
  const bf16_t* Ap = (role == 1) ? Wso_b : Win_b;
  const bf16_t* Bp = (role == 0) ? Wcat_t : (role == 1) ? Wout_t : Wdout_t;

  f4 acc[4][4];
  #pragma unroll
  for (int i = 0; i < 4; ++i)
    #pragma unroll
    for (int j = 0; j < 4; ++j) acc[i][j] = (f4){0.f, 0.f, 0.f, 0.f};

  for (int kt = 0; kt < 8; ++kt) {
    const int k0 = kt << 6;
    __syncthreads();
    #pragma unroll
    for (int i = 0; i < 4; ++i) {
      const int base = (wave * 4 + i) * 64;
      const int cid = base + lane;
      const int row = cid >> 3;
      const int g = (cid & 7) ^ (row & 7);
      async_cp16((char*)As + base * 16,
                 Ap + (size_t)(mb * 128 + row) * 512 + k0 + g * 8);
    }
    #pragma unroll
    for (int i = 0; i < 4; ++i) {
      const int base = (wave * 4 + i) * 64;
      const int cid = base + lane;
      const int row = cid >> 3;
      const int g = (cid & 7) ^ (row & 7);
      async_cp16((char*)Bs + base * 16,
                 Bp + (size_t)(nb * 128 + row) * 512 + k0 + g * 8);
    }
    __syncthreads();
    #pragma unroll
    for (int ks = 0; ks < 2; ++ks) {
      const int gb = ks * 4 + quad;
      bh8 af[4], bfv[4];
      #pragma unroll
      for (int im = 0; im < 4; ++im) {
        const int row = wm + im * 16 + l16;
        af[im] = *(const bh8*)((const char*)As + row * 128 + ((gb ^ (row & 7)) * 16));
      }
      #pragma unroll
      for (int in_ = 0; in_ < 4; ++in_) {
        const int row = wn + in_ * 16 + l16;
        bfv[in_] = *(const bh8*)((const char*)Bs + row * 128 + ((gb ^ (row & 7)) * 16));
      }
      #pragma unroll
      for (int im = 0; im < 4; ++im)
        #pragma unroll
        for (int in_ = 0; in_ < 4; ++in_)
          acc[im][in_] = __builtin_amdgcn_mfma_f32_16x16x32_bf16(af[im], bfv[in_],
                                                                 acc[im][in_], 0, 0, 0);
    }
  }

  #pragma unroll
  for (int im = 0; im < 4; ++im) {
    #pragma unroll
    for (int in_ = 0; in_ < 4; ++in_) {
      const int row0 = mb * 128 + wm + im * 16 + quad * 4;
      const int col = nb * 128 + wn + in_ * 16 + l16;
      if (role == 0) {
        if (col < 192) {
          if (row0 < 512) {
            *(uint2*)(Wproj + (size_t)col * 512 + row0) = pack4bf(acc[im][in_]);
          } else if (row0 == 512) {
            float v = acc[im][in_][0];
            if (col >= 128)     v += b_C[col - 128];
            else if (col >= 64) v += b_B[col - 64];
            biasp[col] = v;
          }
        }
      } else if (role == 1) {
        if (row0 < 64)
          *(uint2*)(Wcat2 + (size_t)col * 576 + row0) = pack4bf(acc[im][in_]);
      } else {
        if (row0 < 512) {
          *(uint2*)(Wcat2 + (size_t)col * 576 + 64 + row0) = pack4bf(acc[im][in_]);
        } else if (row0 == 512) {
          biasW2[col] = acc[im][in_][0];
        }
      }
    }
  }
}

// ---------------- LayerNorm: one wave per row, fp32 -> bf16 ----------------
__global__ __launch_bounds__(256) void ln_kernel(
    const float* __restrict__ x, const float* __restrict__ gamma,
    const float* __restrict__ beta, bf16_t* __restrict__ xn) {
  const int row = blockIdx.x * 4 + (threadIdx.x >> 6);
  const int lane = threadIdx.x & 63;
  const float* xr = x + (size_t)row * 512 + lane * 8;
  float4 v0 = *(const float4*)xr;
  float4 v1 = *(const float4*)(xr + 4);
  float s  = v0.x + v0.y + v0.z + v0.w + v1.x + v1.y + v1.z + v1.w;
  float sq = v0.x*v0.x + v0.y*v0.y + v0.z*v0.z + v0.w*v0.w
           + v1.x*v1.x + v1.y*v1.y + v1.z*v1.z + v1.w*v1.w;
  #pragma unroll
  for (int off = 32; off > 0; off >>= 1) {
    s  += __shfl_xor(s, off, 64);
    sq += __shfl_xor(sq, off, 64);
  }
  const float mu  = s * (1.0f / 512.0f);
  const float var = sq * (1.0f / 512.0f) - mu * mu;
  const float rs  = rsqrtf(var + 1e-3f);
  float4 g0 = *(const float4*)(gamma + lane * 8);
  float4 g1 = *(const float4*)(gamma + lane * 8 + 4);
  float4 b0 = *(const float4*)(beta + lane * 8);
  float4 b1 = *(const float4*)(beta + lane * 8 + 4);
  bh8 ov;
  ov[0] = (short)f2bf((v0.x - mu) * rs * g0.x + b0.x);
  ov[1] = (short)f2bf((v0.y - mu) * rs * g0.y + b0.y);
  ov[2] = (short)f2bf((v0.z - mu) * rs * g0.z + b0.z);
  ov[3] = (short)f2bf((v0.w - mu) * rs * g0.w + b0.w);
  ov[4] = (short)f2bf((v1.x - mu) * rs * g1.x + b1.x);
  ov[5] = (short)f2bf((v1.y - mu) * rs * g1.y + b1.y);
  ov[6] = (short)f2bf((v1.z - mu) * rs * g1.z + b1.z);
  ov[7] = (short)f2bf((v1.w - mu) * rs * g1.w + b1.w);
  *(bh8*)(xn + (size_t)row * 512 + lane * 8) = ov;
}

// ---------------- MFMA GEMM: 128x128 tile, BK=64, 4 waves of 64x64 ----------------
// MODE 2 (proj): projP planar = xn @ Wproj^T (+biasp), cols<192, N grid=2
// MODE 3 (out):  out = [CH|xn] @ Wcat2^T + b_out + biasW2 + x   (K=576)
template <int MODE>
__global__ __launch_bounds__(256, 4) void gemm_mfma(
    const bf16_t* __restrict__ A0, const bf16_t* __restrict__ A1,
    const bf16_t* __restrict__ Wt, int K,
    float* __restrict__ outf,
    const float* __restrict__ bias0, const float* __restrict__ bias1,
    const float* __restrict__ resid) {
  __shared__ __align__(16) bf16_t As[128 * 64];
  __shared__ __align__(16) bf16_t Bs[128 * 64];
  const int tid = threadIdx.x;
  const int wave = tid >> 6, lane = tid & 63;
  const int quad = lane >> 4, l16 = lane & 15;
  const int wm = (wave >> 1) * 64, wn = (wave & 1) * 64;
  const int mb = blockIdx.x, nb = blockIdx.y;

  f4 acc[4][4];
  #pragma unroll
  for (int i = 0; i < 4; ++i)
    #pragma unroll
    for (int j = 0; j < 4; ++j) acc[i][j] = (f4){0.f, 0.f, 0.f, 0.f};

  const int nkt = K >> 6;
  for (int kt = 0; kt < nkt; ++kt) {
    const int k0 = kt << 6;
    const bf16_t* Ap; int lda, kk;
    if (MODE == 3) {
      if (kt == 0) { Ap = A0; lda = 64;  kk = 0; }        // CH tile (K 0..63)
      else         { Ap = A1; lda = 512; kk = k0 - 64; }  // xn tile
    } else { Ap = A0; lda = K; kk = k0; }

    __syncthreads();
    #pragma unroll
    for (int i = 0; i < 4; ++i) {
      const int base = (wave * 4 + i) * 64;
      const int cid = base + lane;
      const int row = cid >> 3;
      const int g = (cid & 7) ^ (row & 7);
      async_cp16((char*)As + base * 16,
                 Ap + (size_t)(mb * 128 + row) * lda + kk + g * 8);
    }
    #pragma unroll
    for (int i = 0; i < 4; ++i) {
      const int base = (wave * 4 + i) * 64;
      const int cid = base + lane;
      const int row = cid >> 3;
      const int g = (cid & 7) ^ (row & 7);
      async_cp16((char*)Bs + base * 16,
                 Wt + (size_t)(nb * 128 + row) * K + k0 + g * 8);
    }
    __syncthreads();

    #pragma unroll
    for (int ks = 0; ks < 2; ++ks) {
      const int gb = ks * 4 + quad;
      bh8 af[4], bfv[4];
      #pragma unroll
      for (int im = 0; im < 4; ++im) {
        const int row = wm + im * 16 + l16;
        af[im] = *(const bh8*)((const char*)As + row * 128 + ((gb ^ (row & 7)) * 16));
      }
      #pragma unroll
      for (int in_ = 0; in_ < 4; ++in_) {
        const int row = wn + in_ * 16 + l16;
        bfv[in_] = *(const bh8*)((const char*)Bs + row * 128 + ((gb ^ (row & 7)) * 16));
      }
      #pragma unroll
      for (int im = 0; im < 4; ++im)
        #pragma unroll
        for (int in_ = 0; in_ < 4; ++in_)
          acc[im][in_] = __builtin_amdgcn_mfma_f32_16x16x32_bf16(af[im], bfv[in_],
                                                                 acc[im][in_], 0, 0, 0);
    }
  }

  // epilogue: C/D layout col=lane&15, row=quad*4+reg
  #pragma unroll
  for (int im = 0; im < 4; ++im) {
    #pragma unroll
    for (int in_ = 0; in_ < 4; ++in_) {
      #pragma unroll
      for (int r = 0; r < 4; ++r) {
        const int row = mb * 128 + wm + im * 16 + quad * 4 + r;
        const int col = nb * 128 + wn + in_ * 16 + l16;
        float v = acc[im][in_][r];
        if (MODE == 2) {
          if (col < 192)
            outf[((size_t)(col >> 6) * M_ROWS + row) * 64 + (col & 63)] = v + bias1[col];
        } else {
          outf[(size_t)row * 512 + col] =
              v + bias0[col] + bias1[col] + resid[(size_t)row * 512 + col];
        }
      }
    }
  }
}

// ---------------- chunked scan: SCAN_C chunks x SCAN_L steps, 512 chains --------
// phase A: chunk-local carries, stored chain-major: carryT[(b*64+n)*SCAN_C + c]
__global__ __launch_bounds__(64) void scan_chunk(
    const float* __restrict__ projP, const float* __restrict__ Abar,
    float* __restrict__ carryT) {
  const int b = blockIdx.x >> 7, c = blockIdx.x & (SCAN_C - 1), n = threadIdx.x;
  const float A = Abar[n];
  const size_t row0 = (size_t)b * 4096 + c * SCAN_L;
  const float* pxs = projP + row0 * 64;
  const float* pB  = projP + ((size_t)M_ROWS + row0) * 64;
  float h = 0.f;
  for (int i = 0; i < SCAN_L; ++i)
    h = fmaf(A, h, pxs[i * 64 + n] * pB[i * 64 + n]);
  carryT[((size_t)(b * 64 + n)) * SCAN_C + c] = h;
}

// phase B+C: each block recomputes its carry-in from the chain-major carries
// (contiguous per thread, L2-resident), then replays its chunk emitting CH=C*h.
__global__ __launch_bounds__(64) void scan_apply(
    const float* __restrict__ projP, const float* __restrict__ Abar,
    const float* __restrict__ Apow, const float* __restrict__ carryT,
    bf16_t* __restrict__ CH) {
  const int b = blockIdx.x >> 7, c = blockIdx.x & (SCAN_C - 1), n = threadIdx.x;
  const float A = Abar[n];
  const float Ap = Apow[n];
  const float* cr = carryT + ((size_t)(b * 64 + n)) * SCAN_C;
  float h = 0.f;
  for (int j = 0; j < c; ++j) h = fmaf(Ap, h, cr[j]);
  const size_t row0 = (size_t)b * 4096 + c * SCAN_L;
  const float* pxs = projP + row0 * 64;
  const float* pB  = projP + ((size_t)M_ROWS + row0) * 64;
  const float* pC  = projP + ((size_t)2 * M_ROWS + row0) * 64;
  bf16_t* o = CH + row0 * 64;
  for (int i = 0; i < SCAN_L; ++i) {
    h = fmaf(A, h, pxs[i * 64 + n] * pB[i * 64 + n]);
    o[i * 64 + n] = f2bf(pC[i * 64 + n] * h);
  }
}

// ---------------- launch ----------------
extern "C" void kernel_launch(void* const* d_in, const int* in_sizes, int n_in,
                              void* d_out, int out_size, void* d_ws, size_t ws_size,
                              hipStream_t stream) {
  const float* x      = (const float*)d_in[0];
  const float* ln_g   = (const float*)d_in[1];
  const float* ln_b   = (const float*)d_in[2];
  const float* W_in   = (const float*)d_in[3];
  const float* b_in   = (const float*)d_in[4];
  const float* W_xs   = (const float*)d_in[5];
  const float* W_B    = (const float*)d_in[6];
  const float* b_B    = (const float*)d_in[7];
  const float* W_C    = (const float*)d_in[8];
  const float* b_C    = (const float*)d_in[9];
  const float* A_log  = (const float*)d_in[10];
  const float* D_skip = (const float*)d_in[11];
  const float* W_so   = (const float*)d_in[12];
  const float* W_out  = (const float*)d_in[13];
  const float* b_out  = (const float*)d_in[14];
  float* out = (float*)d_out;

  char* w = (char*)d_ws;
  auto carve = [&](size_t bytes) {
    char* p = w; w += (bytes + 255) & ~(size_t)255; return p;
  };
  bf16_t* xn     = (bf16_t*)carve((size_t)M_ROWS * 512 * 2);
  float*  projP  = (float*)carve((size_t)3 * M_ROWS * 64 * 4);
  bf16_t* CH     = (bf16_t*)carve((size_t)M_ROWS * 64 * 2);
  float*  carryT = (float*)carve((size_t)8 * 64 * SCAN_C * 4);
  bf16_t* Wproj  = (bf16_t*)carve((size_t)256 * 512 * 2);
  bf16_t* Wcat2  = (bf16_t*)carve((size_t)512 * 576 * 2);
  bf16_t* Win_b  = (bf16_t*)carve((size_t)640 * 512 * 2);
  bf16_t* Wso_b  = (bf16_t*)carve((size_t)128 * 512 * 2);
  bf16_t* Wout_t = (bf16_t*)carve((size_t)512 * 512 * 2);
  bf16_t* Wdout_t= (bf16_t*)carve((size_t)512 * 512 * 2);
  bf16_t* Wcat_t = (bf16_t*)carve((size_t)256 * 512 * 2);
  float*  biasp  = (float*)carve(192 * 4);
  float*  biasW2 = (float*)carve(512 * 4);
  float*  Abar   = (float*)carve(256);
  float*  Apow   = (float*)carve(256);

  prep_all<<<4227, 256, 0, stream>>>(W_in, W_out, W_so, W_xs, W_B, W_C, b_in,
                                     D_skip, A_log, Wout_t, Wdout_t, Win_b,
                                     Wso_b, Wcat_t, Wproj, Abar, Apow);
  gemm_prep<<<34, 256, 0, stream>>>(Win_b, Wcat_t, Wso_b, Wout_t, Wdout_t,
                                    b_B, b_C, Wproj, Wcat2, biasp, biasW2);
  ln_kernel<<<8192, 256, 0, stream>>>(x, ln_g, ln_b, xn);
  gemm_mfma<2><<<dim3(256, 2), 256, 0, stream>>>(xn, nullptr, Wproj, 512,
                                                 projP, nullptr, biasp, nullptr);
  scan_chunk<<<8 * SCAN_C, 64, 0, stream>>>(projP, Abar, carryT);
  scan_apply<<<8 * SCAN_C, 64, 0, stream>>>(projP, Abar, Apow, carryT, CH);
  gemm_mfma<3><<<dim3(256, 4), 256, 0, stream>>>(CH, xn, Wcat2, 576,
                                                 out, b_out, biasW2, x);
}